// Round 7
// baseline (178.582 us; speedup 1.0000x reference)
//
#include <hip/hip_runtime.h>
#include <hip/hip_fp16.h>

// ODEFunc CNF dynamics, B=1e6 rows, H=64:
//   h1 = elu(W1 z + b1); h2 = W2 h1 + b2; out01 = W3 elu(h2)+b3;
//   trace = sum_k elu'(h2_k) * (G ex1)_k with G[k,j]=W2[k,j]*(c_k w0_j + d_k w1_j)
//
// R6 74us -> R7 consts->LDS 74us -> R8 trace-fold + cvt_pk 62.5us -> R9 pk-f32
// at (4,4) 64.6us SPILL regression -> R10 de-spilled (3,3) 58us -> R11 2-tile
// ILP at (2,2) 55.3us -> R12 f16 layer-1 + f16 MFMA 52us.
// R12 counters: VGPR 88 (!), VALUBusy 50%, Occupancy 16.7%, ~38% idle =>
// stall-bound at 2 waves/SIMD while the register footprint shrank to 88.
// The (2,2) pin was sized for R11's projected ~200 regs; it's now 3x too
// conservative. R9's spill was a ~148-reg structure under cap 128; this
// structure needs 88 -> cap 128 is safe.
// R13 (this): single isolated change — waves_per_eu(4,4), grid 2048.
//   4 waves/SIMD double the independent streams covering exp-trans latency
//   and LDS->fma->...->MFMA chains. Spill litmus: WRITE_SIZE must stay
//   11718.75 KB.
// Layouts (m120-verified): A[m=col][k=jt*32+quad*8+jj], B[k][n=col],
//   D[m=mt*16+quad*4+i][n=col].

typedef _Float16 f16x8 __attribute__((ext_vector_type(8)));
typedef _Float16 f16x2 __attribute__((ext_vector_type(2)));
typedef float    f32x4 __attribute__((ext_vector_type(4)));
typedef float    f32x2 __attribute__((ext_vector_type(2)));

#define LO2(v) __builtin_shufflevector(v, v, 0, 1)
#define HI2(v) __builtin_shufflevector(v, v, 2, 3)

// packed 2x f16 exp2 -> 2x v_exp_f16
static __device__ __forceinline__ f16x8 exp2_h8(f16x8 t) {
    f16x8 e;
#pragma unroll
    for (int p = 0; p < 4; ++p) {
        f16x2 t2 = {t[2*p], t[2*p+1]};
        __half2 r = h2exp2(__builtin_bit_cast(__half2, t2));
        f16x2 e2 = __builtin_bit_cast(f16x2, r);
        e[2*p] = e2[0]; e[2*p+1] = e2[1];
    }
    return e;
}

__global__ __launch_bounds__(256) __attribute__((amdgpu_waves_per_eu(4, 4)))
void odefunc_mfma(const float* __restrict__ zin,
                  const float* __restrict__ W1, const float* __restrict__ b1,
                  const float* __restrict__ W2, const float* __restrict__ b2,
                  const float* __restrict__ W3, const float* __restrict__ b3,
                  float* __restrict__ out, int B, int ntiles)
{
    // LDS: layer-1 consts as f16 (f16x8-readable); epilogue consts as f32x4
    __shared__ _Float16 sH[192];   // [0..63]=W1 col0, [64..127]=W1 col1, [128..191]=b1
    __shared__ f32x4    sC[48];    // [0..15]=b2, [16..31]=W3 row0, [32..47]=W3 row1

    const int lane = threadIdx.x & 63;
    const int quad = lane >> 4;      // 0..3
    const int col  = lane & 15;      // row-within-tile

    if (threadIdx.x < 64) {
        int i = threadIdx.x;
        sH[i]       = (_Float16)W1[2*i];
        sH[64 + i]  = (_Float16)W1[2*i + 1];
        sH[128 + i] = (_Float16)b1[i];
        float* s = (float*)sC;
        s[i]       = b2[i];
        s[64 + i]  = W3[i];         // W3[0,:]
        s[128 + i] = W3[64 + i];    // W3[1,:]
    }

    const int wid    = blockIdx.x * (blockDim.x >> 6) + (threadIdx.x >> 6);
    const int nwaves = gridDim.x * (blockDim.x >> 6);

    // ---- Loop-invariant A-operand fragments (f16): W2 and G (trace-folded) ----
    // G[k,j] = W2[k,j] * (W3[0,k]*W1[j,0] + W3[1,k]*W1[j,1])
    f16x8 aW2[4][2], aG[4][2];
#pragma unroll
    for (int mt = 0; mt < 4; ++mt) {
        const int k = mt * 16 + col;
        const float ck = W3[k], dk = W3[64 + k];
#pragma unroll
        for (int jt = 0; jt < 2; ++jt) {
            const float* p = W2 + k * 64 + jt * 32 + quad * 8;
#pragma unroll
            for (int jj = 0; jj < 8; ++jj) {
                int j = jt * 32 + quad * 8 + jj;
                float w2 = p[jj];
                aW2[mt][jt][jj] = (_Float16)w2;
                aG[mt][jt][jj]  = (_Float16)(w2 * fmaf(ck, W1[2*j], dk * W1[2*j+1]));
            }
        }
    }

    const float b30 = b3[0], b31 = b3[1];
    const f32x4 zero4 = {0.f, 0.f, 0.f, 0.f};
    const f32x2 zerop = {0.f, 0.f};
    const f32x2 m1p   = {-1.f, -1.f};
    const f32x2 l2e   = {1.442695040888963f, 1.442695040888963f};
    const _Float16 hl2e = (_Float16)1.442695040888963f;
    const _Float16 hm1  = (_Float16)-1.0f;
    const _Float16 h0   = (_Float16)0.0f;
    const f16x8 zero8 = {h0,h0,h0,h0,h0,h0,h0,h0};
    const f16x8 l2e8  = {hl2e,hl2e,hl2e,hl2e,hl2e,hl2e,hl2e,hl2e};
    const f16x8 m18   = {hm1,hm1,hm1,hm1,hm1,hm1,hm1,hm1};

    __syncthreads();

    // ---- coalesced z: lanes 0-47 cover a tile's 16 rows x 3 floats ----
    const int lload = lane < 48 ? lane : 47;
    int tp = wid;                     // tile-pair index: tiles 2tp, 2tp+1
    float zvA = 0.f, zvB = 0.f;
    if (2 * tp < ntiles) {
        zvA = zin[(2 * tp) * 48 + lload];
        if (2 * tp + 1 < ntiles) zvB = zin[(2 * tp + 1) * 48 + lload];
    }

    int cofs = 0;   // opaque zero: defeats LICM on the LDS re-reads
    for (; 2 * tp < ntiles; tp += nwaves) {
        asm volatile("" : "+v"(cofs));

        const int tA = 2 * tp, tB = 2 * tp + 1;
        const bool vB = tB < ntiles;

        // prefetch next pair's z (hides HBM latency under this pair's compute)
        int tpn = tp + nwaves;
        int tAn = 2 * tpn     < ntiles ? 2 * tpn     : 0;
        int tBn = 2 * tpn + 1 < ntiles ? 2 * tpn + 1 : 0;
        float zvAn = zin[tAn * 48 + lload];
        float zvBn = zin[tBn * 48 + lload];

        float z0A = __shfl(zvA, 3 * col), z1A = __shfl(zvA, 3 * col + 1);
        float z0B = __shfl(zvB, 3 * col), z1B = __shfl(zvB, 3 * col + 1);
        const _Float16 z0Ah = (_Float16)z0A, z1Ah = (_Float16)z1A;
        const _Float16 z0Bh = (_Float16)z0B, z1Bh = (_Float16)z1B;
        const f16x8 z0A8 = {z0Ah,z0Ah,z0Ah,z0Ah,z0Ah,z0Ah,z0Ah,z0Ah};
        const f16x8 z1A8 = {z1Ah,z1Ah,z1Ah,z1Ah,z1Ah,z1Ah,z1Ah,z1Ah};
        const f16x8 z0B8 = {z0Bh,z0Bh,z0Bh,z0Bh,z0Bh,z0Bh,z0Bh,z0Bh};
        const f16x8 z1B8 = {z1Bh,z1Bh,z1Bh,z1Bh,z1Bh,z1Bh,z1Bh,z1Bh};

        // ---- layer 1 (branch-free elu, packed f16): fragments ARE the results ----
        f16x8 BhA[2], BeA[2], BhB[2], BeB[2];
#pragma unroll
        for (int jt = 0; jt < 2; ++jt) {
            int j0 = cofs + jt * 32 + quad * 8;
            f16x8 w0v = *(const f16x8*)(sH + j0);
            f16x8 w1v = *(const f16x8*)(sH + j0 + 64);
            f16x8 bbv = *(const f16x8*)(sH + j0 + 128);
            // tile A
            f16x8 aA = __builtin_elementwise_fma(w0v, z0A8,
                       __builtin_elementwise_fma(w1v, z1A8, bbv));
            f16x8 eA = exp2_h8(__builtin_elementwise_min(aA, zero8) * l2e8);
            f16x8 hA = __builtin_elementwise_max(aA, eA + m18);
            // tile B (independent chain)
            f16x8 aB = __builtin_elementwise_fma(w0v, z0B8,
                       __builtin_elementwise_fma(w1v, z1B8, bbv));
            f16x8 eB = exp2_h8(__builtin_elementwise_min(aB, zero8) * l2e8);
            f16x8 hB = __builtin_elementwise_max(aB, eB + m18);
            BhA[jt] = hA; BeA[jt] = eA;
            BhB[jt] = hB; BeB[jt] = eB;
        }

        // ---- MFMA (f16): accH = W2*h^T + b2 (C-init), accT = G*e^T ----
        f32x4 aHA[4], aTA[4], aHB[4], aTB[4];
#pragma unroll
        for (int mt = 0; mt < 4; ++mt) {
            f32x4 b2v = sC[cofs + mt * 4 + quad];   // k0 = mt*16+quad*4, shared A/B
            aHA[mt] = __builtin_amdgcn_mfma_f32_16x16x32_f16(aW2[mt][0], BhA[0], b2v, 0, 0, 0);
            aHA[mt] = __builtin_amdgcn_mfma_f32_16x16x32_f16(aW2[mt][1], BhA[1], aHA[mt], 0, 0, 0);
            aHB[mt] = __builtin_amdgcn_mfma_f32_16x16x32_f16(aW2[mt][0], BhB[0], b2v, 0, 0, 0);
            aHB[mt] = __builtin_amdgcn_mfma_f32_16x16x32_f16(aW2[mt][1], BhB[1], aHB[mt], 0, 0, 0);
            aTA[mt] = __builtin_amdgcn_mfma_f32_16x16x32_f16(aG[mt][0], BeA[0], zero4, 0, 0, 0);
            aTA[mt] = __builtin_amdgcn_mfma_f32_16x16x32_f16(aG[mt][1], BeA[1], aTA[mt], 0, 0, 0);
            aTB[mt] = __builtin_amdgcn_mfma_f32_16x16x32_f16(aG[mt][0], BeB[0], zero4, 0, 0, 0);
            aTB[mt] = __builtin_amdgcn_mfma_f32_16x16x32_f16(aG[mt][1], BeB[1], aTB[mt], 0, 0, 0);
        }

        // ---- epilogue (f32): elu + W3 fold; trace = ex2 . accT ----
        f32x2 o0A = zerop, o1A = zerop, trA = zerop;
        f32x2 o0B = zerop, o1B = zerop, trB = zerop;
#pragma unroll
        for (int mt = 0; mt < 4; ++mt) {
            int k4 = cofs + mt * 4 + quad;      // f32x4 idx of k0 = mt*16+quad*4
            f32x4 w30 = sC[k4 + 16];
            f32x4 w31 = sC[k4 + 32];
#pragma unroll
            for (int half = 0; half < 2; ++half) {
                f32x2 w30p = half ? HI2(w30) : LO2(w30);
                f32x2 w31p = half ? HI2(w31) : LO2(w31);
                // tile A
                f32x2 a2A = half ? HI2(aHA[mt]) : LO2(aHA[mt]);   // b2 already in
                f32x2 atA = half ? HI2(aTA[mt]) : LO2(aTA[mt]);
                f32x2 tmA = __builtin_elementwise_min(a2A, zerop) * l2e;
                f32x2 e2A = { __builtin_amdgcn_exp2f(tmA[0]),
                              __builtin_amdgcn_exp2f(tmA[1]) };
                f32x2 hhA = __builtin_elementwise_max(a2A, e2A + m1p);
                o0A = __builtin_elementwise_fma(w30p, hhA, o0A);
                o1A = __builtin_elementwise_fma(w31p, hhA, o1A);
                trA = __builtin_elementwise_fma(e2A, atA, trA);
                // tile B
                f32x2 a2B = half ? HI2(aHB[mt]) : LO2(aHB[mt]);
                f32x2 atB = half ? HI2(aTB[mt]) : LO2(aTB[mt]);
                f32x2 tmB = __builtin_elementwise_min(a2B, zerop) * l2e;
                f32x2 e2B = { __builtin_amdgcn_exp2f(tmB[0]),
                              __builtin_amdgcn_exp2f(tmB[1]) };
                f32x2 hhB = __builtin_elementwise_max(a2B, e2B + m1p);
                o0B = __builtin_elementwise_fma(w30p, hhB, o0B);
                o1B = __builtin_elementwise_fma(w31p, hhB, o1B);
                trB = __builtin_elementwise_fma(e2B, atB, trB);
            }
        }
        float o0a = o0A[0] + o0A[1], o1a = o1A[0] + o1A[1], tra = trA[0] + trA[1];
        float o0b = o0B[0] + o0B[1], o1b = o1B[0] + o1B[1], trb = trB[0] + trB[1];

        // ---- cross-quad reduction (k spans quads): 2 butterfly stages ----
        o0a += __shfl_xor(o0a, 16); o0a += __shfl_xor(o0a, 32);
        o1a += __shfl_xor(o1a, 16); o1a += __shfl_xor(o1a, 32);
        tra += __shfl_xor(tra, 16); tra += __shfl_xor(tra, 32);
        o0b += __shfl_xor(o0b, 16); o0b += __shfl_xor(o0b, 32);
        o1b += __shfl_xor(o1b, 16); o1b += __shfl_xor(o1b, 32);
        trb += __shfl_xor(trb, 16); trb += __shfl_xor(trb, 32);

        int rowA = tA * 16 + col;
        if (lane < 16 && rowA < B) {
            out[3 * rowA + 0] = o0a + b30;
            out[3 * rowA + 1] = o1a + b31;
            out[3 * rowA + 2] = -tra;
        }
        int rowB = tB * 16 + col;
        if (lane < 16 && vB && rowB < B) {
            out[3 * rowB + 0] = o0b + b30;
            out[3 * rowB + 1] = o1b + b31;
            out[3 * rowB + 2] = -trb;
        }

        zvA = zvAn;
        zvB = zvBn;
    }
}

extern "C" void kernel_launch(void* const* d_in, const int* in_sizes, int n_in,
                              void* d_out, int out_size, void* d_ws, size_t ws_size,
                              hipStream_t stream) {
    // d_in: 0=t(unused) 1=z_and_logp 2=W1 3=b1 4=W2 5=b2 6=W3 7=b3
    const float* zin = (const float*)d_in[1];
    const float* W1  = (const float*)d_in[2];
    const float* b1  = (const float*)d_in[3];
    const float* W2  = (const float*)d_in[4];
    const float* b2  = (const float*)d_in[5];
    const float* W3  = (const float*)d_in[6];
    const float* b3  = (const float*)d_in[7];
    float* out = (float*)d_out;

    int B = in_sizes[1] / 3;
    int ntiles = (B + 15) / 16;
    int grid = 2048;   // 4 waves/SIMD -> 1024 resident blocks -> 2 rounds
    odefunc_mfma<<<grid, 256, 0, stream>>>(zin, W1, b1, W2, b2, W3, b3,
                                           out, B, ntiles);
}

// Round 8
// 128.264 us; speedup vs baseline: 1.3923x; 1.3923x over previous
//
#include <hip/hip_runtime.h>
#include <hip/hip_fp16.h>

// ODEFunc CNF dynamics, B=1e6 rows, H=64:
//   h1 = elu(W1 z + b1); h2 = W2 h1 + b2; out01 = W3 elu(h2)+b3;
//   trace = sum_k elu'(h2_k) * (G ex1)_k with G[k,j]=W2[k,j]*(c_k w0_j + d_k w1_j)
//
// Ladder: R6 74us -> R7 consts->LDS 74 -> R8 trace-fold+cvt_pk 62.5 ->
// R9 (4,4) SPILL 64.6 -> R10 (3,3) 58 -> R11 2-tile ILP (2,2) 55.3 ->
// R12 f16 layer-1 + f16 MFMA 52 -> R13 (4,4) SPILL DISASTER 110us.
//
// waves_per_eu ledger (empirical, gfx950):
//   (2,2): no pressure, but max=2 clamps occupancy -> 38% idle (R12)
//   (3,3): 68-84 VGPR, no spill (R7/R10)
//   (4,4): allocator budgets 64 arch-VGPRs (unified-file split) -> total
//          spill, 320MB scratch traffic, dur = scratch BW (R9, R13). NEVER.
// R14 (this): single isolated change from R12 — REMOVE the attribute.
//   No min -> no register cap -> spill impossible from pressure.
//   No max -> occupancy purely resource-derived: ~88-120 regs ->
//   floor(512/regs) = 4-5 waves/SIMD (2x R12's residency) to cover the
//   38% idle (exp-trans latency + LDS->fma->MFMA chains).
//   Grid 1024 -> 2048 so the grid doesn't cap residency.
//   Spill litmus: WRITE_SIZE must stay 11718.75 KB, FETCH ~5985 KB.
// Layouts (m120-verified): A[m=col][k=jt*32+quad*8+jj], B[k][n=col],
//   D[m=mt*16+quad*4+i][n=col].

typedef _Float16 f16x8 __attribute__((ext_vector_type(8)));
typedef _Float16 f16x2 __attribute__((ext_vector_type(2)));
typedef float    f32x4 __attribute__((ext_vector_type(4)));
typedef float    f32x2 __attribute__((ext_vector_type(2)));

#define LO2(v) __builtin_shufflevector(v, v, 0, 1)
#define HI2(v) __builtin_shufflevector(v, v, 2, 3)

// packed 2x f16 exp2 -> 2x v_exp_f16
static __device__ __forceinline__ f16x8 exp2_h8(f16x8 t) {
    f16x8 e;
#pragma unroll
    for (int p = 0; p < 4; ++p) {
        f16x2 t2 = {t[2*p], t[2*p+1]};
        __half2 r = h2exp2(__builtin_bit_cast(__half2, t2));
        f16x2 e2 = __builtin_bit_cast(f16x2, r);
        e[2*p] = e2[0]; e[2*p+1] = e2[1];
    }
    return e;
}

__global__ __launch_bounds__(256)
void odefunc_mfma(const float* __restrict__ zin,
                  const float* __restrict__ W1, const float* __restrict__ b1,
                  const float* __restrict__ W2, const float* __restrict__ b2,
                  const float* __restrict__ W3, const float* __restrict__ b3,
                  float* __restrict__ out, int B, int ntiles)
{
    // LDS: layer-1 consts as f16 (f16x8-readable); epilogue consts as f32x4
    __shared__ _Float16 sH[192];   // [0..63]=W1 col0, [64..127]=W1 col1, [128..191]=b1
    __shared__ f32x4    sC[48];    // [0..15]=b2, [16..31]=W3 row0, [32..47]=W3 row1

    const int lane = threadIdx.x & 63;
    const int quad = lane >> 4;      // 0..3
    const int col  = lane & 15;      // row-within-tile

    if (threadIdx.x < 64) {
        int i = threadIdx.x;
        sH[i]       = (_Float16)W1[2*i];
        sH[64 + i]  = (_Float16)W1[2*i + 1];
        sH[128 + i] = (_Float16)b1[i];
        float* s = (float*)sC;
        s[i]       = b2[i];
        s[64 + i]  = W3[i];         // W3[0,:]
        s[128 + i] = W3[64 + i];    // W3[1,:]
    }

    const int wid    = blockIdx.x * (blockDim.x >> 6) + (threadIdx.x >> 6);
    const int nwaves = gridDim.x * (blockDim.x >> 6);

    // ---- Loop-invariant A-operand fragments (f16): W2 and G (trace-folded) ----
    // G[k,j] = W2[k,j] * (W3[0,k]*W1[j,0] + W3[1,k]*W1[j,1])
    f16x8 aW2[4][2], aG[4][2];
#pragma unroll
    for (int mt = 0; mt < 4; ++mt) {
        const int k = mt * 16 + col;
        const float ck = W3[k], dk = W3[64 + k];
#pragma unroll
        for (int jt = 0; jt < 2; ++jt) {
            const float* p = W2 + k * 64 + jt * 32 + quad * 8;
#pragma unroll
            for (int jj = 0; jj < 8; ++jj) {
                int j = jt * 32 + quad * 8 + jj;
                float w2 = p[jj];
                aW2[mt][jt][jj] = (_Float16)w2;
                aG[mt][jt][jj]  = (_Float16)(w2 * fmaf(ck, W1[2*j], dk * W1[2*j+1]));
            }
        }
    }

    const float b30 = b3[0], b31 = b3[1];
    const f32x4 zero4 = {0.f, 0.f, 0.f, 0.f};
    const f32x2 zerop = {0.f, 0.f};
    const f32x2 m1p   = {-1.f, -1.f};
    const f32x2 l2e   = {1.442695040888963f, 1.442695040888963f};
    const _Float16 hl2e = (_Float16)1.442695040888963f;
    const _Float16 hm1  = (_Float16)-1.0f;
    const _Float16 h0   = (_Float16)0.0f;
    const f16x8 zero8 = {h0,h0,h0,h0,h0,h0,h0,h0};
    const f16x8 l2e8  = {hl2e,hl2e,hl2e,hl2e,hl2e,hl2e,hl2e,hl2e};
    const f16x8 m18   = {hm1,hm1,hm1,hm1,hm1,hm1,hm1,hm1};

    __syncthreads();

    // ---- coalesced z: lanes 0-47 cover a tile's 16 rows x 3 floats ----
    const int lload = lane < 48 ? lane : 47;
    int tp = wid;                     // tile-pair index: tiles 2tp, 2tp+1
    float zvA = 0.f, zvB = 0.f;
    if (2 * tp < ntiles) {
        zvA = zin[(2 * tp) * 48 + lload];
        if (2 * tp + 1 < ntiles) zvB = zin[(2 * tp + 1) * 48 + lload];
    }

    int cofs = 0;   // opaque zero: defeats LICM on the LDS re-reads
    for (; 2 * tp < ntiles; tp += nwaves) {
        asm volatile("" : "+v"(cofs));

        const int tA = 2 * tp, tB = 2 * tp + 1;
        const bool vB = tB < ntiles;

        // prefetch next pair's z (hides HBM latency under this pair's compute)
        int tpn = tp + nwaves;
        int tAn = 2 * tpn     < ntiles ? 2 * tpn     : 0;
        int tBn = 2 * tpn + 1 < ntiles ? 2 * tpn + 1 : 0;
        float zvAn = zin[tAn * 48 + lload];
        float zvBn = zin[tBn * 48 + lload];

        float z0A = __shfl(zvA, 3 * col), z1A = __shfl(zvA, 3 * col + 1);
        float z0B = __shfl(zvB, 3 * col), z1B = __shfl(zvB, 3 * col + 1);
        const _Float16 z0Ah = (_Float16)z0A, z1Ah = (_Float16)z1A;
        const _Float16 z0Bh = (_Float16)z0B, z1Bh = (_Float16)z1B;
        const f16x8 z0A8 = {z0Ah,z0Ah,z0Ah,z0Ah,z0Ah,z0Ah,z0Ah,z0Ah};
        const f16x8 z1A8 = {z1Ah,z1Ah,z1Ah,z1Ah,z1Ah,z1Ah,z1Ah,z1Ah};
        const f16x8 z0B8 = {z0Bh,z0Bh,z0Bh,z0Bh,z0Bh,z0Bh,z0Bh,z0Bh};
        const f16x8 z1B8 = {z1Bh,z1Bh,z1Bh,z1Bh,z1Bh,z1Bh,z1Bh,z1Bh};

        // ---- layer 1 (branch-free elu, packed f16): fragments ARE the results ----
        f16x8 BhA[2], BeA[2], BhB[2], BeB[2];
#pragma unroll
        for (int jt = 0; jt < 2; ++jt) {
            int j0 = cofs + jt * 32 + quad * 8;
            f16x8 w0v = *(const f16x8*)(sH + j0);
            f16x8 w1v = *(const f16x8*)(sH + j0 + 64);
            f16x8 bbv = *(const f16x8*)(sH + j0 + 128);
            // tile A
            f16x8 aA = __builtin_elementwise_fma(w0v, z0A8,
                       __builtin_elementwise_fma(w1v, z1A8, bbv));
            f16x8 eA = exp2_h8(__builtin_elementwise_min(aA, zero8) * l2e8);
            f16x8 hA = __builtin_elementwise_max(aA, eA + m18);
            // tile B (independent chain)
            f16x8 aB = __builtin_elementwise_fma(w0v, z0B8,
                       __builtin_elementwise_fma(w1v, z1B8, bbv));
            f16x8 eB = exp2_h8(__builtin_elementwise_min(aB, zero8) * l2e8);
            f16x8 hB = __builtin_elementwise_max(aB, eB + m18);
            BhA[jt] = hA; BeA[jt] = eA;
            BhB[jt] = hB; BeB[jt] = eB;
        }

        // ---- MFMA (f16): accH = W2*h^T + b2 (C-init), accT = G*e^T ----
        f32x4 aHA[4], aTA[4], aHB[4], aTB[4];
#pragma unroll
        for (int mt = 0; mt < 4; ++mt) {
            f32x4 b2v = sC[cofs + mt * 4 + quad];   // k0 = mt*16+quad*4, shared A/B
            aHA[mt] = __builtin_amdgcn_mfma_f32_16x16x32_f16(aW2[mt][0], BhA[0], b2v, 0, 0, 0);
            aHA[mt] = __builtin_amdgcn_mfma_f32_16x16x32_f16(aW2[mt][1], BhA[1], aHA[mt], 0, 0, 0);
            aHB[mt] = __builtin_amdgcn_mfma_f32_16x16x32_f16(aW2[mt][0], BhB[0], b2v, 0, 0, 0);
            aHB[mt] = __builtin_amdgcn_mfma_f32_16x16x32_f16(aW2[mt][1], BhB[1], aHB[mt], 0, 0, 0);
            aTA[mt] = __builtin_amdgcn_mfma_f32_16x16x32_f16(aG[mt][0], BeA[0], zero4, 0, 0, 0);
            aTA[mt] = __builtin_amdgcn_mfma_f32_16x16x32_f16(aG[mt][1], BeA[1], aTA[mt], 0, 0, 0);
            aTB[mt] = __builtin_amdgcn_mfma_f32_16x16x32_f16(aG[mt][0], BeB[0], zero4, 0, 0, 0);
            aTB[mt] = __builtin_amdgcn_mfma_f32_16x16x32_f16(aG[mt][1], BeB[1], aTB[mt], 0, 0, 0);
        }

        // ---- epilogue (f32): elu + W3 fold; trace = ex2 . accT ----
        f32x2 o0A = zerop, o1A = zerop, trA = zerop;
        f32x2 o0B = zerop, o1B = zerop, trB = zerop;
#pragma unroll
        for (int mt = 0; mt < 4; ++mt) {
            int k4 = cofs + mt * 4 + quad;      // f32x4 idx of k0 = mt*16+quad*4
            f32x4 w30 = sC[k4 + 16];
            f32x4 w31 = sC[k4 + 32];
#pragma unroll
            for (int half = 0; half < 2; ++half) {
                f32x2 w30p = half ? HI2(w30) : LO2(w30);
                f32x2 w31p = half ? HI2(w31) : LO2(w31);
                // tile A
                f32x2 a2A = half ? HI2(aHA[mt]) : LO2(aHA[mt]);   // b2 already in
                f32x2 atA = half ? HI2(aTA[mt]) : LO2(aTA[mt]);
                f32x2 tmA = __builtin_elementwise_min(a2A, zerop) * l2e;
                f32x2 e2A = { __builtin_amdgcn_exp2f(tmA[0]),
                              __builtin_amdgcn_exp2f(tmA[1]) };
                f32x2 hhA = __builtin_elementwise_max(a2A, e2A + m1p);
                o0A = __builtin_elementwise_fma(w30p, hhA, o0A);
                o1A = __builtin_elementwise_fma(w31p, hhA, o1A);
                trA = __builtin_elementwise_fma(e2A, atA, trA);
                // tile B
                f32x2 a2B = half ? HI2(aHB[mt]) : LO2(aHB[mt]);
                f32x2 atB = half ? HI2(aTB[mt]) : LO2(aTB[mt]);
                f32x2 tmB = __builtin_elementwise_min(a2B, zerop) * l2e;
                f32x2 e2B = { __builtin_amdgcn_exp2f(tmB[0]),
                              __builtin_amdgcn_exp2f(tmB[1]) };
                f32x2 hhB = __builtin_elementwise_max(a2B, e2B + m1p);
                o0B = __builtin_elementwise_fma(w30p, hhB, o0B);
                o1B = __builtin_elementwise_fma(w31p, hhB, o1B);
                trB = __builtin_elementwise_fma(e2B, atB, trB);
            }
        }
        float o0a = o0A[0] + o0A[1], o1a = o1A[0] + o1A[1], tra = trA[0] + trA[1];
        float o0b = o0B[0] + o0B[1], o1b = o1B[0] + o1B[1], trb = trB[0] + trB[1];

        // ---- cross-quad reduction (k spans quads): 2 butterfly stages ----
        o0a += __shfl_xor(o0a, 16); o0a += __shfl_xor(o0a, 32);
        o1a += __shfl_xor(o1a, 16); o1a += __shfl_xor(o1a, 32);
        tra += __shfl_xor(tra, 16); tra += __shfl_xor(tra, 32);
        o0b += __shfl_xor(o0b, 16); o0b += __shfl_xor(o0b, 32);
        o1b += __shfl_xor(o1b, 16); o1b += __shfl_xor(o1b, 32);
        trb += __shfl_xor(trb, 16); trb += __shfl_xor(trb, 32);

        int rowA = tA * 16 + col;
        if (lane < 16 && rowA < B) {
            out[3 * rowA + 0] = o0a + b30;
            out[3 * rowA + 1] = o1a + b31;
            out[3 * rowA + 2] = -tra;
        }
        int rowB = tB * 16 + col;
        if (lane < 16 && vB && rowB < B) {
            out[3 * rowB + 0] = o0b + b30;
            out[3 * rowB + 1] = o1b + b31;
            out[3 * rowB + 2] = -trb;
        }

        zvA = zvAn;
        zvB = zvBn;
    }
}

extern "C" void kernel_launch(void* const* d_in, const int* in_sizes, int n_in,
                              void* d_out, int out_size, void* d_ws, size_t ws_size,
                              hipStream_t stream) {
    // d_in: 0=t(unused) 1=z_and_logp 2=W1 3=b1 4=W2 5=b2 6=W3 7=b3
    const float* zin = (const float*)d_in[1];
    const float* W1  = (const float*)d_in[2];
    const float* b1  = (const float*)d_in[3];
    const float* W2  = (const float*)d_in[4];
    const float* b2  = (const float*)d_in[5];
    const float* W3  = (const float*)d_in[6];
    const float* b3  = (const float*)d_in[7];
    float* out = (float*)d_out;

    int B = in_sizes[1] / 3;
    int ntiles = (B + 15) / 16;
    int grid = 2048;   // don't cap residency; occupancy is resource-derived
    odefunc_mfma<<<grid, 256, 0, stream>>>(zin, W1, b1, W2, b2, W3, b3,
                                           out, B, ntiles);
}

// Round 9
// 119.294 us; speedup vs baseline: 1.4970x; 1.0752x over previous
//
#include <hip/hip_runtime.h>
#include <hip/hip_fp16.h>

// ODEFunc CNF dynamics, B=1e6 rows, H=64:
//   h1 = elu(W1 z + b1); h2 = W2 h1 + b2; out01 = W3 elu(h2)+b3;
//   trace = sum_k elu'(h2_k) * (G ex1)_k with G[k,j]=W2[k,j]*(c_k w0_j + d_k w1_j)
//
// Ladder: R6 74us -> R7 consts->LDS 74 -> R8 trace-fold+cvt_pk 62.5 ->
// R9 (4,4) SPILL 64.6 -> R10 (3,3) 58 -> R11 2-tile ILP (2,2) 55.3 ->
// R12 f16 layer-1 + f16 MFMA 52 -> R13 (4,4) SPILL 110 -> R14 no-attr 62.2
// (VGPR 112, occupancy UNCHANGED 18.4%, VALU stream +27% fatter: no-pin
//  codegen is worse — SGPR 112->32, uniform work pushed to VALU).
//
// waves_per_eu ledger (empirical, gfx950, this kernel family):
//   (2,2): 88 VGPR, clean, 52us (R12 best)
//   (3,3): 68-84 VGPR, never spilled (R7, R10) — cap 168 >> ~88 needed
//   (4,4): allocator budgets 64 arch-VGPRs -> total spill (R9, R13). NEVER.
//   none : 112 VGPR, no occupancy gain, fatter stream, 62us (R14)
// R15 (this): the untested quadrant — single isolated change from R12:
//   waves_per_eu(2,2) -> (3,3), grid 1024 -> 1536. +50% resident waves to
//   absorb R12's 38% idle (exp-trans latency + LDS->fma->MFMA chains), with
//   pinned-codegen quality and zero spill risk.
//   Spill litmus: WRITE_SIZE must stay 11718.75 KB, FETCH ~5988 KB.
// Layouts (m120-verified): A[m=col][k=jt*32+quad*8+jj], B[k][n=col],
//   D[m=mt*16+quad*4+i][n=col].

typedef _Float16 f16x8 __attribute__((ext_vector_type(8)));
typedef _Float16 f16x2 __attribute__((ext_vector_type(2)));
typedef float    f32x4 __attribute__((ext_vector_type(4)));
typedef float    f32x2 __attribute__((ext_vector_type(2)));

#define LO2(v) __builtin_shufflevector(v, v, 0, 1)
#define HI2(v) __builtin_shufflevector(v, v, 2, 3)

// packed 2x f16 exp2 -> 2x v_exp_f16
static __device__ __forceinline__ f16x8 exp2_h8(f16x8 t) {
    f16x8 e;
#pragma unroll
    for (int p = 0; p < 4; ++p) {
        f16x2 t2 = {t[2*p], t[2*p+1]};
        __half2 r = h2exp2(__builtin_bit_cast(__half2, t2));
        f16x2 e2 = __builtin_bit_cast(f16x2, r);
        e[2*p] = e2[0]; e[2*p+1] = e2[1];
    }
    return e;
}

__global__ __launch_bounds__(256) __attribute__((amdgpu_waves_per_eu(3, 3)))
void odefunc_mfma(const float* __restrict__ zin,
                  const float* __restrict__ W1, const float* __restrict__ b1,
                  const float* __restrict__ W2, const float* __restrict__ b2,
                  const float* __restrict__ W3, const float* __restrict__ b3,
                  float* __restrict__ out, int B, int ntiles)
{
    // LDS: layer-1 consts as f16 (f16x8-readable); epilogue consts as f32x4
    __shared__ _Float16 sH[192];   // [0..63]=W1 col0, [64..127]=W1 col1, [128..191]=b1
    __shared__ f32x4    sC[48];    // [0..15]=b2, [16..31]=W3 row0, [32..47]=W3 row1

    const int lane = threadIdx.x & 63;
    const int quad = lane >> 4;      // 0..3
    const int col  = lane & 15;      // row-within-tile

    if (threadIdx.x < 64) {
        int i = threadIdx.x;
        sH[i]       = (_Float16)W1[2*i];
        sH[64 + i]  = (_Float16)W1[2*i + 1];
        sH[128 + i] = (_Float16)b1[i];
        float* s = (float*)sC;
        s[i]       = b2[i];
        s[64 + i]  = W3[i];         // W3[0,:]
        s[128 + i] = W3[64 + i];    // W3[1,:]
    }

    const int wid    = blockIdx.x * (blockDim.x >> 6) + (threadIdx.x >> 6);
    const int nwaves = gridDim.x * (blockDim.x >> 6);

    // ---- Loop-invariant A-operand fragments (f16): W2 and G (trace-folded) ----
    // G[k,j] = W2[k,j] * (W3[0,k]*W1[j,0] + W3[1,k]*W1[j,1])
    f16x8 aW2[4][2], aG[4][2];
#pragma unroll
    for (int mt = 0; mt < 4; ++mt) {
        const int k = mt * 16 + col;
        const float ck = W3[k], dk = W3[64 + k];
#pragma unroll
        for (int jt = 0; jt < 2; ++jt) {
            const float* p = W2 + k * 64 + jt * 32 + quad * 8;
#pragma unroll
            for (int jj = 0; jj < 8; ++jj) {
                int j = jt * 32 + quad * 8 + jj;
                float w2 = p[jj];
                aW2[mt][jt][jj] = (_Float16)w2;
                aG[mt][jt][jj]  = (_Float16)(w2 * fmaf(ck, W1[2*j], dk * W1[2*j+1]));
            }
        }
    }

    const float b30 = b3[0], b31 = b3[1];
    const f32x4 zero4 = {0.f, 0.f, 0.f, 0.f};
    const f32x2 zerop = {0.f, 0.f};
    const f32x2 m1p   = {-1.f, -1.f};
    const f32x2 l2e   = {1.442695040888963f, 1.442695040888963f};
    const _Float16 hl2e = (_Float16)1.442695040888963f;
    const _Float16 hm1  = (_Float16)-1.0f;
    const _Float16 h0   = (_Float16)0.0f;
    const f16x8 zero8 = {h0,h0,h0,h0,h0,h0,h0,h0};
    const f16x8 l2e8  = {hl2e,hl2e,hl2e,hl2e,hl2e,hl2e,hl2e,hl2e};
    const f16x8 m18   = {hm1,hm1,hm1,hm1,hm1,hm1,hm1,hm1};

    __syncthreads();

    // ---- coalesced z: lanes 0-47 cover a tile's 16 rows x 3 floats ----
    const int lload = lane < 48 ? lane : 47;
    int tp = wid;                     // tile-pair index: tiles 2tp, 2tp+1
    float zvA = 0.f, zvB = 0.f;
    if (2 * tp < ntiles) {
        zvA = zin[(2 * tp) * 48 + lload];
        if (2 * tp + 1 < ntiles) zvB = zin[(2 * tp + 1) * 48 + lload];
    }

    int cofs = 0;   // opaque zero: defeats LICM on the LDS re-reads
    for (; 2 * tp < ntiles; tp += nwaves) {
        asm volatile("" : "+v"(cofs));

        const int tA = 2 * tp, tB = 2 * tp + 1;
        const bool vB = tB < ntiles;

        // prefetch next pair's z (hides HBM latency under this pair's compute)
        int tpn = tp + nwaves;
        int tAn = 2 * tpn     < ntiles ? 2 * tpn     : 0;
        int tBn = 2 * tpn + 1 < ntiles ? 2 * tpn + 1 : 0;
        float zvAn = zin[tAn * 48 + lload];
        float zvBn = zin[tBn * 48 + lload];

        float z0A = __shfl(zvA, 3 * col), z1A = __shfl(zvA, 3 * col + 1);
        float z0B = __shfl(zvB, 3 * col), z1B = __shfl(zvB, 3 * col + 1);
        const _Float16 z0Ah = (_Float16)z0A, z1Ah = (_Float16)z1A;
        const _Float16 z0Bh = (_Float16)z0B, z1Bh = (_Float16)z1B;
        const f16x8 z0A8 = {z0Ah,z0Ah,z0Ah,z0Ah,z0Ah,z0Ah,z0Ah,z0Ah};
        const f16x8 z1A8 = {z1Ah,z1Ah,z1Ah,z1Ah,z1Ah,z1Ah,z1Ah,z1Ah};
        const f16x8 z0B8 = {z0Bh,z0Bh,z0Bh,z0Bh,z0Bh,z0Bh,z0Bh,z0Bh};
        const f16x8 z1B8 = {z1Bh,z1Bh,z1Bh,z1Bh,z1Bh,z1Bh,z1Bh,z1Bh};

        // ---- layer 1 (branch-free elu, packed f16): fragments ARE the results ----
        f16x8 BhA[2], BeA[2], BhB[2], BeB[2];
#pragma unroll
        for (int jt = 0; jt < 2; ++jt) {
            int j0 = cofs + jt * 32 + quad * 8;
            f16x8 w0v = *(const f16x8*)(sH + j0);
            f16x8 w1v = *(const f16x8*)(sH + j0 + 64);
            f16x8 bbv = *(const f16x8*)(sH + j0 + 128);
            // tile A
            f16x8 aA = __builtin_elementwise_fma(w0v, z0A8,
                       __builtin_elementwise_fma(w1v, z1A8, bbv));
            f16x8 eA = exp2_h8(__builtin_elementwise_min(aA, zero8) * l2e8);
            f16x8 hA = __builtin_elementwise_max(aA, eA + m18);
            // tile B (independent chain)
            f16x8 aB = __builtin_elementwise_fma(w0v, z0B8,
                       __builtin_elementwise_fma(w1v, z1B8, bbv));
            f16x8 eB = exp2_h8(__builtin_elementwise_min(aB, zero8) * l2e8);
            f16x8 hB = __builtin_elementwise_max(aB, eB + m18);
            BhA[jt] = hA; BeA[jt] = eA;
            BhB[jt] = hB; BeB[jt] = eB;
        }

        // ---- MFMA (f16): accH = W2*h^T + b2 (C-init), accT = G*e^T ----
        f32x4 aHA[4], aTA[4], aHB[4], aTB[4];
#pragma unroll
        for (int mt = 0; mt < 4; ++mt) {
            f32x4 b2v = sC[cofs + mt * 4 + quad];   // k0 = mt*16+quad*4, shared A/B
            aHA[mt] = __builtin_amdgcn_mfma_f32_16x16x32_f16(aW2[mt][0], BhA[0], b2v, 0, 0, 0);
            aHA[mt] = __builtin_amdgcn_mfma_f32_16x16x32_f16(aW2[mt][1], BhA[1], aHA[mt], 0, 0, 0);
            aHB[mt] = __builtin_amdgcn_mfma_f32_16x16x32_f16(aW2[mt][0], BhB[0], b2v, 0, 0, 0);
            aHB[mt] = __builtin_amdgcn_mfma_f32_16x16x32_f16(aW2[mt][1], BhB[1], aHB[mt], 0, 0, 0);
            aTA[mt] = __builtin_amdgcn_mfma_f32_16x16x32_f16(aG[mt][0], BeA[0], zero4, 0, 0, 0);
            aTA[mt] = __builtin_amdgcn_mfma_f32_16x16x32_f16(aG[mt][1], BeA[1], aTA[mt], 0, 0, 0);
            aTB[mt] = __builtin_amdgcn_mfma_f32_16x16x32_f16(aG[mt][0], BeB[0], zero4, 0, 0, 0);
            aTB[mt] = __builtin_amdgcn_mfma_f32_16x16x32_f16(aG[mt][1], BeB[1], aTB[mt], 0, 0, 0);
        }

        // ---- epilogue (f32): elu + W3 fold; trace = ex2 . accT ----
        f32x2 o0A = zerop, o1A = zerop, trA = zerop;
        f32x2 o0B = zerop, o1B = zerop, trB = zerop;
#pragma unroll
        for (int mt = 0; mt < 4; ++mt) {
            int k4 = cofs + mt * 4 + quad;      // f32x4 idx of k0 = mt*16+quad*4
            f32x4 w30 = sC[k4 + 16];
            f32x4 w31 = sC[k4 + 32];
#pragma unroll
            for (int half = 0; half < 2; ++half) {
                f32x2 w30p = half ? HI2(w30) : LO2(w30);
                f32x2 w31p = half ? HI2(w31) : LO2(w31);
                // tile A
                f32x2 a2A = half ? HI2(aHA[mt]) : LO2(aHA[mt]);   // b2 already in
                f32x2 atA = half ? HI2(aTA[mt]) : LO2(aTA[mt]);
                f32x2 tmA = __builtin_elementwise_min(a2A, zerop) * l2e;
                f32x2 e2A = { __builtin_amdgcn_exp2f(tmA[0]),
                              __builtin_amdgcn_exp2f(tmA[1]) };
                f32x2 hhA = __builtin_elementwise_max(a2A, e2A + m1p);
                o0A = __builtin_elementwise_fma(w30p, hhA, o0A);
                o1A = __builtin_elementwise_fma(w31p, hhA, o1A);
                trA = __builtin_elementwise_fma(e2A, atA, trA);
                // tile B
                f32x2 a2B = half ? HI2(aHB[mt]) : LO2(aHB[mt]);
                f32x2 atB = half ? HI2(aTB[mt]) : LO2(aTB[mt]);
                f32x2 tmB = __builtin_elementwise_min(a2B, zerop) * l2e;
                f32x2 e2B = { __builtin_amdgcn_exp2f(tmB[0]),
                              __builtin_amdgcn_exp2f(tmB[1]) };
                f32x2 hhB = __builtin_elementwise_max(a2B, e2B + m1p);
                o0B = __builtin_elementwise_fma(w30p, hhB, o0B);
                o1B = __builtin_elementwise_fma(w31p, hhB, o1B);
                trB = __builtin_elementwise_fma(e2B, atB, trB);
            }
        }
        float o0a = o0A[0] + o0A[1], o1a = o1A[0] + o1A[1], tra = trA[0] + trA[1];
        float o0b = o0B[0] + o0B[1], o1b = o1B[0] + o1B[1], trb = trB[0] + trB[1];

        // ---- cross-quad reduction (k spans quads): 2 butterfly stages ----
        o0a += __shfl_xor(o0a, 16); o0a += __shfl_xor(o0a, 32);
        o1a += __shfl_xor(o1a, 16); o1a += __shfl_xor(o1a, 32);
        tra += __shfl_xor(tra, 16); tra += __shfl_xor(tra, 32);
        o0b += __shfl_xor(o0b, 16); o0b += __shfl_xor(o0b, 32);
        o1b += __shfl_xor(o1b, 16); o1b += __shfl_xor(o1b, 32);
        trb += __shfl_xor(trb, 16); trb += __shfl_xor(trb, 32);

        int rowA = tA * 16 + col;
        if (lane < 16 && rowA < B) {
            out[3 * rowA + 0] = o0a + b30;
            out[3 * rowA + 1] = o1a + b31;
            out[3 * rowA + 2] = -tra;
        }
        int rowB = tB * 16 + col;
        if (lane < 16 && vB && rowB < B) {
            out[3 * rowB + 0] = o0b + b30;
            out[3 * rowB + 1] = o1b + b31;
            out[3 * rowB + 2] = -trb;
        }

        zvA = zvAn;
        zvB = zvBn;
    }
}

extern "C" void kernel_launch(void* const* d_in, const int* in_sizes, int n_in,
                              void* d_out, int out_size, void* d_ws, size_t ws_size,
                              hipStream_t stream) {
    // d_in: 0=t(unused) 1=z_and_logp 2=W1 3=b1 4=W2 5=b2 6=W3 7=b3
    const float* zin = (const float*)d_in[1];
    const float* W1  = (const float*)d_in[2];
    const float* b1  = (const float*)d_in[3];
    const float* W2  = (const float*)d_in[4];
    const float* b2  = (const float*)d_in[5];
    const float* W3  = (const float*)d_in[6];
    const float* b3  = (const float*)d_in[7];
    float* out = (float*)d_out;

    int B = in_sizes[1] / 3;
    int ntiles = (B + 15) / 16;
    int grid = 1536;   // 3 waves/SIMD -> 768 resident blocks -> 2 rounds
    odefunc_mfma<<<grid, 256, 0, stream>>>(zin, W1, b1, W2, b2, W3, b3,
                                           out, B, ntiles);
}

// Round 10
// 119.172 us; speedup vs baseline: 1.4985x; 1.0010x over previous
//
#include <hip/hip_runtime.h>
#include <hip/hip_fp16.h>

// ODEFunc CNF dynamics, B=1e6 rows, H=64:
//   h1 = elu(W1 z + b1); h2 = W2 h1 + b2; out01 = W3 elu(h2)+b3;
//   trace = sum_k elu'(h2_k) * (G ex1)_k with G[k,j]=W2[k,j]*(c_k w0_j + d_k w1_j)
//
// Ladder: R6 74 -> R7 74 -> R8 62.5 -> R9 SPILL 64.6 -> R10 58 -> R11 55.3 ->
// R12 f16 52 -> R13 SPILL 110 -> R14 no-attr 62.2 -> R15 (3,3) 50.6.
//
// R15 lesson: occupancy +42% -> time -3%. Idle ~47% is NOT wave-coverable.
// Register model fix: VGPR_Count excludes AGPR accumulators (~64). True
// unified use ~148 -> (4,4) cap 128 always spilled; (3,3) cap 168 has no
// hoist headroom. The per-iteration stall: cofs forces 18 ds_reads/iter
// with a pinned schedule -> all waves lgkmcnt-stall in lockstep at layer-1.
// R16 (this): constants -> registers, ZERO LDS reads in the loop, (2,2):
//   - cw0/cw1/cbb (f16, 24 regs) + cb2/cw30/cw31 (f32, 48 regs) hoisted
//   - cofs + asm hack deleted (it was the R7-era register-war fix; obsolete)
//   - needs cap 256 -> waves_per_eu(2,2), grid 1024
//   - loop body: shfl z, f16 layer-1, 32 MFMA, f32 epilogue, 12 shfl_xor
//   Spill litmus: WRITE_SIZE must stay 11718.75 KB, FETCH ~5988 KB.
// Layouts (m120-verified): A[m=col][k=jt*32+quad*8+jj], B[k][n=col],
//   D[m=mt*16+quad*4+i][n=col].

typedef _Float16 f16x8 __attribute__((ext_vector_type(8)));
typedef _Float16 f16x2 __attribute__((ext_vector_type(2)));
typedef float    f32x4 __attribute__((ext_vector_type(4)));
typedef float    f32x2 __attribute__((ext_vector_type(2)));

#define LO2(v) __builtin_shufflevector(v, v, 0, 1)
#define HI2(v) __builtin_shufflevector(v, v, 2, 3)

// packed 2x f16 exp2 -> 2x v_exp_f16
static __device__ __forceinline__ f16x8 exp2_h8(f16x8 t) {
    f16x8 e;
#pragma unroll
    for (int p = 0; p < 4; ++p) {
        f16x2 t2 = {t[2*p], t[2*p+1]};
        __half2 r = h2exp2(__builtin_bit_cast(__half2, t2));
        f16x2 e2 = __builtin_bit_cast(f16x2, r);
        e[2*p] = e2[0]; e[2*p+1] = e2[1];
    }
    return e;
}

__global__ __launch_bounds__(256) __attribute__((amdgpu_waves_per_eu(2, 2)))
void odefunc_mfma(const float* __restrict__ zin,
                  const float* __restrict__ W1, const float* __restrict__ b1,
                  const float* __restrict__ W2, const float* __restrict__ b2,
                  const float* __restrict__ W3, const float* __restrict__ b3,
                  float* __restrict__ out, int B, int ntiles)
{
    // LDS used only as a one-shot staging area for coalesced const loads
    __shared__ _Float16 sH[192];   // [0..63]=W1 col0, [64..127]=W1 col1, [128..191]=b1
    __shared__ f32x4    sC[48];    // [0..15]=b2, [16..31]=W3 row0, [32..47]=W3 row1

    const int lane = threadIdx.x & 63;
    const int quad = lane >> 4;      // 0..3
    const int col  = lane & 15;      // row-within-tile

    if (threadIdx.x < 64) {
        int i = threadIdx.x;
        sH[i]       = (_Float16)W1[2*i];
        sH[64 + i]  = (_Float16)W1[2*i + 1];
        sH[128 + i] = (_Float16)b1[i];
        float* s = (float*)sC;
        s[i]       = b2[i];
        s[64 + i]  = W3[i];         // W3[0,:]
        s[128 + i] = W3[64 + i];    // W3[1,:]
    }

    const int wid    = blockIdx.x * (blockDim.x >> 6) + (threadIdx.x >> 6);
    const int nwaves = gridDim.x * (blockDim.x >> 6);

    // ---- Loop-invariant A-operand fragments (f16): W2 and G (trace-folded) ----
    // G[k,j] = W2[k,j] * (W3[0,k]*W1[j,0] + W3[1,k]*W1[j,1])
    f16x8 aW2[4][2], aG[4][2];
#pragma unroll
    for (int mt = 0; mt < 4; ++mt) {
        const int k = mt * 16 + col;
        const float ck = W3[k], dk = W3[64 + k];
#pragma unroll
        for (int jt = 0; jt < 2; ++jt) {
            const float* p = W2 + k * 64 + jt * 32 + quad * 8;
#pragma unroll
            for (int jj = 0; jj < 8; ++jj) {
                int j = jt * 32 + quad * 8 + jj;
                float w2 = p[jj];
                aW2[mt][jt][jj] = (_Float16)w2;
                aG[mt][jt][jj]  = (_Float16)(w2 * fmaf(ck, W1[2*j], dk * W1[2*j+1]));
            }
        }
    }

    const float b30 = b3[0], b31 = b3[1];
    const f32x4 zero4 = {0.f, 0.f, 0.f, 0.f};
    const f32x2 zerop = {0.f, 0.f};
    const f32x2 m1p   = {-1.f, -1.f};
    const f32x2 l2e   = {1.442695040888963f, 1.442695040888963f};
    const _Float16 hl2e = (_Float16)1.442695040888963f;
    const _Float16 hm1  = (_Float16)-1.0f;
    const _Float16 h0   = (_Float16)0.0f;
    const f16x8 zero8 = {h0,h0,h0,h0,h0,h0,h0,h0};
    const f16x8 l2e8  = {hl2e,hl2e,hl2e,hl2e,hl2e,hl2e,hl2e,hl2e};
    const f16x8 m18   = {hm1,hm1,hm1,hm1,hm1,hm1,hm1,hm1};

    __syncthreads();

    // ---- hoist per-lane constants into registers (R16: no LDS in loop) ----
    f16x8 cw0[2], cw1[2], cbb[2];
#pragma unroll
    for (int jt = 0; jt < 2; ++jt) {
        int j0 = jt * 32 + quad * 8;
        cw0[jt] = *(const f16x8*)(sH + j0);
        cw1[jt] = *(const f16x8*)(sH + j0 + 64);
        cbb[jt] = *(const f16x8*)(sH + j0 + 128);
    }
    f32x4 cb2[4], cw30[4], cw31[4];
#pragma unroll
    for (int mt = 0; mt < 4; ++mt) {
        int k4 = mt * 4 + quad;
        cb2[mt]  = sC[k4];
        cw30[mt] = sC[k4 + 16];
        cw31[mt] = sC[k4 + 32];
    }

    // ---- coalesced z: lanes 0-47 cover a tile's 16 rows x 3 floats ----
    const int lload = lane < 48 ? lane : 47;
    int tp = wid;                     // tile-pair index: tiles 2tp, 2tp+1
    float zvA = 0.f, zvB = 0.f;
    if (2 * tp < ntiles) {
        zvA = zin[(2 * tp) * 48 + lload];
        if (2 * tp + 1 < ntiles) zvB = zin[(2 * tp + 1) * 48 + lload];
    }

    for (; 2 * tp < ntiles; tp += nwaves) {
        const int tA = 2 * tp, tB = 2 * tp + 1;
        const bool vB = tB < ntiles;

        // prefetch next pair's z (hides HBM latency under this pair's compute)
        int tpn = tp + nwaves;
        int tAn = 2 * tpn     < ntiles ? 2 * tpn     : 0;
        int tBn = 2 * tpn + 1 < ntiles ? 2 * tpn + 1 : 0;
        float zvAn = zin[tAn * 48 + lload];
        float zvBn = zin[tBn * 48 + lload];

        float z0A = __shfl(zvA, 3 * col), z1A = __shfl(zvA, 3 * col + 1);
        float z0B = __shfl(zvB, 3 * col), z1B = __shfl(zvB, 3 * col + 1);
        const _Float16 z0Ah = (_Float16)z0A, z1Ah = (_Float16)z1A;
        const _Float16 z0Bh = (_Float16)z0B, z1Bh = (_Float16)z1B;
        const f16x8 z0A8 = {z0Ah,z0Ah,z0Ah,z0Ah,z0Ah,z0Ah,z0Ah,z0Ah};
        const f16x8 z1A8 = {z1Ah,z1Ah,z1Ah,z1Ah,z1Ah,z1Ah,z1Ah,z1Ah};
        const f16x8 z0B8 = {z0Bh,z0Bh,z0Bh,z0Bh,z0Bh,z0Bh,z0Bh,z0Bh};
        const f16x8 z1B8 = {z1Bh,z1Bh,z1Bh,z1Bh,z1Bh,z1Bh,z1Bh,z1Bh};

        // ---- layer 1 (branch-free elu, packed f16): fragments ARE the results ----
        f16x8 BhA[2], BeA[2], BhB[2], BeB[2];
#pragma unroll
        for (int jt = 0; jt < 2; ++jt) {
            // tile A
            f16x8 aA = __builtin_elementwise_fma(cw0[jt], z0A8,
                       __builtin_elementwise_fma(cw1[jt], z1A8, cbb[jt]));
            f16x8 eA = exp2_h8(__builtin_elementwise_min(aA, zero8) * l2e8);
            f16x8 hA = __builtin_elementwise_max(aA, eA + m18);
            // tile B (independent chain)
            f16x8 aB = __builtin_elementwise_fma(cw0[jt], z0B8,
                       __builtin_elementwise_fma(cw1[jt], z1B8, cbb[jt]));
            f16x8 eB = exp2_h8(__builtin_elementwise_min(aB, zero8) * l2e8);
            f16x8 hB = __builtin_elementwise_max(aB, eB + m18);
            BhA[jt] = hA; BeA[jt] = eA;
            BhB[jt] = hB; BeB[jt] = eB;
        }

        // ---- MFMA (f16): accH = W2*h^T + b2 (C-init), accT = G*e^T ----
        f32x4 aHA[4], aTA[4], aHB[4], aTB[4];
#pragma unroll
        for (int mt = 0; mt < 4; ++mt) {
            aHA[mt] = __builtin_amdgcn_mfma_f32_16x16x32_f16(aW2[mt][0], BhA[0], cb2[mt], 0, 0, 0);
            aHA[mt] = __builtin_amdgcn_mfma_f32_16x16x32_f16(aW2[mt][1], BhA[1], aHA[mt], 0, 0, 0);
            aHB[mt] = __builtin_amdgcn_mfma_f32_16x16x32_f16(aW2[mt][0], BhB[0], cb2[mt], 0, 0, 0);
            aHB[mt] = __builtin_amdgcn_mfma_f32_16x16x32_f16(aW2[mt][1], BhB[1], aHB[mt], 0, 0, 0);
            aTA[mt] = __builtin_amdgcn_mfma_f32_16x16x32_f16(aG[mt][0], BeA[0], zero4, 0, 0, 0);
            aTA[mt] = __builtin_amdgcn_mfma_f32_16x16x32_f16(aG[mt][1], BeA[1], aTA[mt], 0, 0, 0);
            aTB[mt] = __builtin_amdgcn_mfma_f32_16x16x32_f16(aG[mt][0], BeB[0], zero4, 0, 0, 0);
            aTB[mt] = __builtin_amdgcn_mfma_f32_16x16x32_f16(aG[mt][1], BeB[1], aTB[mt], 0, 0, 0);
        }

        // ---- epilogue (f32): elu + W3 fold; trace = ex2 . accT ----
        f32x2 o0A = zerop, o1A = zerop, trA = zerop;
        f32x2 o0B = zerop, o1B = zerop, trB = zerop;
#pragma unroll
        for (int mt = 0; mt < 4; ++mt) {
#pragma unroll
            for (int half = 0; half < 2; ++half) {
                f32x2 w30p = half ? HI2(cw30[mt]) : LO2(cw30[mt]);
                f32x2 w31p = half ? HI2(cw31[mt]) : LO2(cw31[mt]);
                // tile A
                f32x2 a2A = half ? HI2(aHA[mt]) : LO2(aHA[mt]);   // b2 already in
                f32x2 atA = half ? HI2(aTA[mt]) : LO2(aTA[mt]);
                f32x2 tmA = __builtin_elementwise_min(a2A, zerop) * l2e;
                f32x2 e2A = { __builtin_amdgcn_exp2f(tmA[0]),
                              __builtin_amdgcn_exp2f(tmA[1]) };
                f32x2 hhA = __builtin_elementwise_max(a2A, e2A + m1p);
                o0A = __builtin_elementwise_fma(w30p, hhA, o0A);
                o1A = __builtin_elementwise_fma(w31p, hhA, o1A);
                trA = __builtin_elementwise_fma(e2A, atA, trA);
                // tile B
                f32x2 a2B = half ? HI2(aHB[mt]) : LO2(aHB[mt]);
                f32x2 atB = half ? HI2(aTB[mt]) : LO2(aTB[mt]);
                f32x2 tmB = __builtin_elementwise_min(a2B, zerop) * l2e;
                f32x2 e2B = { __builtin_amdgcn_exp2f(tmB[0]),
                              __builtin_amdgcn_exp2f(tmB[1]) };
                f32x2 hhB = __builtin_elementwise_max(a2B, e2B + m1p);
                o0B = __builtin_elementwise_fma(w30p, hhB, o0B);
                o1B = __builtin_elementwise_fma(w31p, hhB, o1B);
                trB = __builtin_elementwise_fma(e2B, atB, trB);
            }
        }
        float o0a = o0A[0] + o0A[1], o1a = o1A[0] + o1A[1], tra = trA[0] + trA[1];
        float o0b = o0B[0] + o0B[1], o1b = o1B[0] + o1B[1], trb = trB[0] + trB[1];

        // ---- cross-quad reduction (k spans quads): 2 butterfly stages ----
        o0a += __shfl_xor(o0a, 16); o0a += __shfl_xor(o0a, 32);
        o1a += __shfl_xor(o1a, 16); o1a += __shfl_xor(o1a, 32);
        tra += __shfl_xor(tra, 16); tra += __shfl_xor(tra, 32);
        o0b += __shfl_xor(o0b, 16); o0b += __shfl_xor(o0b, 32);
        o1b += __shfl_xor(o1b, 16); o1b += __shfl_xor(o1b, 32);
        trb += __shfl_xor(trb, 16); trb += __shfl_xor(trb, 32);

        int rowA = tA * 16 + col;
        if (lane < 16 && rowA < B) {
            out[3 * rowA + 0] = o0a + b30;
            out[3 * rowA + 1] = o1a + b31;
            out[3 * rowA + 2] = -tra;
        }
        int rowB = tB * 16 + col;
        if (lane < 16 && vB && rowB < B) {
            out[3 * rowB + 0] = o0b + b30;
            out[3 * rowB + 1] = o1b + b31;
            out[3 * rowB + 2] = -trb;
        }

        zvA = zvAn;
        zvB = zvBn;
    }
}

extern "C" void kernel_launch(void* const* d_in, const int* in_sizes, int n_in,
                              void* d_out, int out_size, void* d_ws, size_t ws_size,
                              hipStream_t stream) {
    // d_in: 0=t(unused) 1=z_and_logp 2=W1 3=b1 4=W2 5=b2 6=W3 7=b3
    const float* zin = (const float*)d_in[1];
    const float* W1  = (const float*)d_in[2];
    const float* b1  = (const float*)d_in[3];
    const float* W2  = (const float*)d_in[4];
    const float* b2  = (const float*)d_in[5];
    const float* W3  = (const float*)d_in[6];
    const float* b3  = (const float*)d_in[7];
    float* out = (float*)d_out;

    int B = in_sizes[1] / 3;
    int ntiles = (B + 15) / 16;
    int grid = 1024;   // 2 waves/SIMD -> 512 resident blocks -> 2 rounds
    odefunc_mfma<<<grid, 256, 0, stream>>>(zin, W1, b1, W2, b2, W3, b3,
                                           out, B, ntiles);
}

// Round 12
// 115.531 us; speedup vs baseline: 1.5458x; 1.0315x over previous
//
#include <hip/hip_runtime.h>
#include <hip/hip_fp16.h>

// ODEFunc CNF dynamics, B=1e6 rows, H=64:
//   h1 = elu(W1 z + b1); h2 = W2 h1 + b2; out01 = W3 elu(h2)+b3;
//   trace = sum_k elu'(h2_k) * (G ex1)_k with G[k,j]=W2[k,j]*(c_k w0_j + d_k w1_j)
//
// Ladder: R6 74 -> R8 62.5 -> R10 58 -> R11 55.3 -> R12 f16 layer-1 52 ->
// R15 (3,3) 50.6 -> R16 consts->regs 49.5. R17: compile error (cvt_pkrtz
// returns __fp16 vector; needs bit_cast to _Float16 vector) — fixed here,
// logic identical.
// R16 accounting: wall/pair 3895 cyc = 2 waves x 1950 cyc VALU issue. Wall ==
// total issue demand. Only cheaper CYCLES help. The f32 epilogue (~550 cyc/
// pair, 32 of 48 trans ops) is the last f32-rate block.
// R17/R18: (a) l2e pre-scale fold (EXACT): W1,b1,b2 *= log2e; W3 /= log2e at
//   init. elu: e=exp2(min(a',0)); h'=max(a',fma(l2e,e,-l2e)) — mul+add
//   collapse into one fma; accH = l2e*h2pre arrives pre-scaled for epilogue
//   exp2. aW2/aG unchanged.
// (b) full-f16 epilogue: cvt_pkrtz acc->f16x2, pk_min/pk_fma/pk_max at 2cyc/
//   2elem (true double rate), h2exp2 halves trans 32->16. Cross-quad
//   reduction stays f32. absmax predict <=0.009 vs threshold 1.77e-2.
// Layouts (m120-verified): A[m=col][k=jt*32+quad*8+jj], B[k][n=col],
//   D[m=mt*16+quad*4+i][n=col].

typedef _Float16 f16x8 __attribute__((ext_vector_type(8)));
typedef _Float16 f16x2 __attribute__((ext_vector_type(2)));
typedef float    f32x4 __attribute__((ext_vector_type(4)));

static __device__ __forceinline__ f16x8 exp2_h8(f16x8 t) {
    f16x8 e;
#pragma unroll
    for (int p = 0; p < 4; ++p) {
        f16x2 t2 = {t[2*p], t[2*p+1]};
        __half2 r = h2exp2(__builtin_bit_cast(__half2, t2));
        f16x2 e2 = __builtin_bit_cast(f16x2, r);
        e[2*p] = e2[0]; e[2*p+1] = e2[1];
    }
    return e;
}

static __device__ __forceinline__ f16x2 exp2_h2(f16x2 t) {
    __half2 r = h2exp2(__builtin_bit_cast(__half2, t));
    return __builtin_bit_cast(f16x2, r);
}

static __device__ __forceinline__ f16x2 cvtpk(float a, float b) {
    return __builtin_bit_cast(f16x2, __builtin_amdgcn_cvt_pkrtz(a, b));
}

__global__ __launch_bounds__(256) __attribute__((amdgpu_waves_per_eu(2, 2)))
void odefunc_mfma(const float* __restrict__ zin,
                  const float* __restrict__ W1, const float* __restrict__ b1,
                  const float* __restrict__ W2, const float* __restrict__ b2,
                  const float* __restrict__ W3, const float* __restrict__ b3,
                  float* __restrict__ out, int B, int ntiles)
{
    const float L2E  = 1.442695040888963f;
    const float RL2E = 0.6931471805599453f;   // 1/log2(e) = ln 2

    // LDS: one-shot staging for coalesced const loads (pre-scaled by l2e fold)
    __shared__ _Float16 sH[192];   // l2e*W1 col0 | l2e*W1 col1 | l2e*b1
    __shared__ f32x4    sC[48];    // l2e*b2 | W3row0/l2e | W3row1/l2e

    const int lane = threadIdx.x & 63;
    const int quad = lane >> 4;      // 0..3
    const int col  = lane & 15;      // row-within-tile

    if (threadIdx.x < 64) {
        int i = threadIdx.x;
        sH[i]       = (_Float16)(W1[2*i]     * L2E);
        sH[64 + i]  = (_Float16)(W1[2*i + 1] * L2E);
        sH[128 + i] = (_Float16)(b1[i]       * L2E);
        float* s = (float*)sC;
        s[i]       = b2[i] * L2E;
        s[64 + i]  = W3[i]      * RL2E;   // W3[0,:]/l2e
        s[128 + i] = W3[64 + i] * RL2E;   // W3[1,:]/l2e
    }

    const int wid    = blockIdx.x * (blockDim.x >> 6) + (threadIdx.x >> 6);
    const int nwaves = gridDim.x * (blockDim.x >> 6);

    // ---- Loop-invariant A-fragments (f16): W2 and G (trace-folded), UNSCALED ----
    f16x8 aW2[4][2], aG[4][2];
#pragma unroll
    for (int mt = 0; mt < 4; ++mt) {
        const int k = mt * 16 + col;
        const float ck = W3[k], dk = W3[64 + k];
#pragma unroll
        for (int jt = 0; jt < 2; ++jt) {
            const float* p = W2 + k * 64 + jt * 32 + quad * 8;
#pragma unroll
            for (int jj = 0; jj < 8; ++jj) {
                int j = jt * 32 + quad * 8 + jj;
                float w2 = p[jj];
                aW2[mt][jt][jj] = (_Float16)w2;
                aG[mt][jt][jj]  = (_Float16)(w2 * fmaf(ck, W1[2*j], dk * W1[2*j+1]));
            }
        }
    }

    const float b30 = b3[0], b31 = b3[1];
    const f32x4 zero4 = {0.f, 0.f, 0.f, 0.f};
    const _Float16 hl2e = (_Float16)L2E;
    const _Float16 h0   = (_Float16)0.0f;
    const f16x8 zero8 = {h0,h0,h0,h0,h0,h0,h0,h0};
    const f16x8 l2e8  = {hl2e,hl2e,hl2e,hl2e,hl2e,hl2e,hl2e,hl2e};
    const f16x8 ml2e8 = {-hl2e,-hl2e,-hl2e,-hl2e,-hl2e,-hl2e,-hl2e,-hl2e};
    const f16x2 zero2 = {h0, h0};
    const f16x2 l2e2  = {hl2e, hl2e};
    const f16x2 ml2e2 = {-hl2e, -hl2e};

    __syncthreads();

    // ---- hoist per-lane constants into registers ----
    f16x8 cw0[2], cw1[2], cbb[2];
#pragma unroll
    for (int jt = 0; jt < 2; ++jt) {
        int j0 = jt * 32 + quad * 8;
        cw0[jt] = *(const f16x8*)(sH + j0);
        cw1[jt] = *(const f16x8*)(sH + j0 + 64);
        cbb[jt] = *(const f16x8*)(sH + j0 + 128);
    }
    f32x4 cb2[4];
    f16x2 cw30h[4][2], cw31h[4][2];
#pragma unroll
    for (int mt = 0; mt < 4; ++mt) {
        int k4 = mt * 4 + quad;
        cb2[mt] = sC[k4];                       // l2e*b2 -> MFMA C-init
        f32x4 w30 = sC[k4 + 16];
        f32x4 w31 = sC[k4 + 32];
        cw30h[mt][0] = cvtpk(w30[0], w30[1]);
        cw30h[mt][1] = cvtpk(w30[2], w30[3]);
        cw31h[mt][0] = cvtpk(w31[0], w31[1]);
        cw31h[mt][1] = cvtpk(w31[2], w31[3]);
    }

    // ---- coalesced z: lanes 0-47 cover a tile's 16 rows x 3 floats ----
    const int lload = lane < 48 ? lane : 47;
    int tp = wid;                     // tile-pair index: tiles 2tp, 2tp+1
    float zvA = 0.f, zvB = 0.f;
    if (2 * tp < ntiles) {
        zvA = zin[(2 * tp) * 48 + lload];
        if (2 * tp + 1 < ntiles) zvB = zin[(2 * tp + 1) * 48 + lload];
    }

    for (; 2 * tp < ntiles; tp += nwaves) {
        const int tA = 2 * tp, tB = 2 * tp + 1;
        const bool vB = tB < ntiles;

        // prefetch next pair's z (covered by this pair's ~4k-cycle body)
        int tpn = tp + nwaves;
        int tAn = 2 * tpn     < ntiles ? 2 * tpn     : 0;
        int tBn = 2 * tpn + 1 < ntiles ? 2 * tpn + 1 : 0;
        float zvAn = zin[tAn * 48 + lload];
        float zvBn = zin[tBn * 48 + lload];

        float z0A = __shfl(zvA, 3 * col), z1A = __shfl(zvA, 3 * col + 1);
        float z0B = __shfl(zvB, 3 * col), z1B = __shfl(zvB, 3 * col + 1);
        const _Float16 z0Ah = (_Float16)z0A, z1Ah = (_Float16)z1A;
        const _Float16 z0Bh = (_Float16)z0B, z1Bh = (_Float16)z1B;
        const f16x8 z0A8 = {z0Ah,z0Ah,z0Ah,z0Ah,z0Ah,z0Ah,z0Ah,z0Ah};
        const f16x8 z1A8 = {z1Ah,z1Ah,z1Ah,z1Ah,z1Ah,z1Ah,z1Ah,z1Ah};
        const f16x8 z0B8 = {z0Bh,z0Bh,z0Bh,z0Bh,z0Bh,z0Bh,z0Bh,z0Bh};
        const f16x8 z1B8 = {z1Bh,z1Bh,z1Bh,z1Bh,z1Bh,z1Bh,z1Bh,z1Bh};

        // ---- layer 1: a' = l2e*a (pre-scaled consts); e = exp2(min(a',0));
        //      Bh' = l2e*elu(a) = max(a', fma(l2e,e,-l2e)) ----
        f16x8 BhA[2], BeA[2], BhB[2], BeB[2];
#pragma unroll
        for (int jt = 0; jt < 2; ++jt) {
            // tile A
            f16x8 aA = __builtin_elementwise_fma(cw0[jt], z0A8,
                       __builtin_elementwise_fma(cw1[jt], z1A8, cbb[jt]));
            f16x8 eA = exp2_h8(__builtin_elementwise_min(aA, zero8));
            f16x8 hA = __builtin_elementwise_max(aA,
                       __builtin_elementwise_fma(l2e8, eA, ml2e8));
            // tile B (independent chain)
            f16x8 aB = __builtin_elementwise_fma(cw0[jt], z0B8,
                       __builtin_elementwise_fma(cw1[jt], z1B8, cbb[jt]));
            f16x8 eB = exp2_h8(__builtin_elementwise_min(aB, zero8));
            f16x8 hB = __builtin_elementwise_max(aB,
                       __builtin_elementwise_fma(l2e8, eB, ml2e8));
            BhA[jt] = hA; BeA[jt] = eA;
            BhB[jt] = hB; BeB[jt] = eB;
        }

        // ---- MFMA: accH = W2*(l2e*h) + l2e*b2 = l2e*h2pre; accT = G*e ----
        f32x4 aHA[4], aTA[4], aHB[4], aTB[4];
#pragma unroll
        for (int mt = 0; mt < 4; ++mt) {
            aHA[mt] = __builtin_amdgcn_mfma_f32_16x16x32_f16(aW2[mt][0], BhA[0], cb2[mt], 0, 0, 0);
            aHA[mt] = __builtin_amdgcn_mfma_f32_16x16x32_f16(aW2[mt][1], BhA[1], aHA[mt], 0, 0, 0);
            aHB[mt] = __builtin_amdgcn_mfma_f32_16x16x32_f16(aW2[mt][0], BhB[0], cb2[mt], 0, 0, 0);
            aHB[mt] = __builtin_amdgcn_mfma_f32_16x16x32_f16(aW2[mt][1], BhB[1], aHB[mt], 0, 0, 0);
            aTA[mt] = __builtin_amdgcn_mfma_f32_16x16x32_f16(aG[mt][0], BeA[0], zero4, 0, 0, 0);
            aTA[mt] = __builtin_amdgcn_mfma_f32_16x16x32_f16(aG[mt][1], BeA[1], aTA[mt], 0, 0, 0);
            aTB[mt] = __builtin_amdgcn_mfma_f32_16x16x32_f16(aG[mt][0], BeB[0], zero4, 0, 0, 0);
            aTB[mt] = __builtin_amdgcn_mfma_f32_16x16x32_f16(aG[mt][1], BeB[1], aTB[mt], 0, 0, 0);
        }

        // ---- epilogue (packed f16, true double-rate): e2 = exp2(min(acc,0));
        //      hh' = max(acc, fma(l2e,e2,-l2e)); folds in pk_fma_f16 ----
        f16x2 o0A2 = zero2, o1A2 = zero2, trA2 = zero2;
        f16x2 o0B2 = zero2, o1B2 = zero2, trB2 = zero2;
#pragma unroll
        for (int mt = 0; mt < 4; ++mt) {
#pragma unroll
            for (int p = 0; p < 2; ++p) {
                f16x2 w30p = cw30h[mt][p], w31p = cw31h[mt][p];
                // tile A
                f16x2 ahA = cvtpk(aHA[mt][2*p], aHA[mt][2*p+1]);
                f16x2 atA = cvtpk(aTA[mt][2*p], aTA[mt][2*p+1]);
                f16x2 eA  = exp2_h2(__builtin_elementwise_min(ahA, zero2));
                f16x2 hhA = __builtin_elementwise_max(ahA,
                            __builtin_elementwise_fma(l2e2, eA, ml2e2));
                o0A2 = __builtin_elementwise_fma(w30p, hhA, o0A2);
                o1A2 = __builtin_elementwise_fma(w31p, hhA, o1A2);
                trA2 = __builtin_elementwise_fma(eA, atA, trA2);
                // tile B
                f16x2 ahB = cvtpk(aHB[mt][2*p], aHB[mt][2*p+1]);
                f16x2 atB = cvtpk(aTB[mt][2*p], aTB[mt][2*p+1]);
                f16x2 eB  = exp2_h2(__builtin_elementwise_min(ahB, zero2));
                f16x2 hhB = __builtin_elementwise_max(ahB,
                            __builtin_elementwise_fma(l2e2, eB, ml2e2));
                o0B2 = __builtin_elementwise_fma(w30p, hhB, o0B2);
                o1B2 = __builtin_elementwise_fma(w31p, hhB, o1B2);
                trB2 = __builtin_elementwise_fma(eB, atB, trB2);
            }
        }
        float o0a = (float)o0A2[0] + (float)o0A2[1];
        float o1a = (float)o1A2[0] + (float)o1A2[1];
        float tra = (float)trA2[0] + (float)trA2[1];
        float o0b = (float)o0B2[0] + (float)o0B2[1];
        float o1b = (float)o1B2[0] + (float)o1B2[1];
        float trb = (float)trB2[0] + (float)trB2[1];

        // ---- cross-quad reduction (k spans quads): 2 butterfly stages, f32 ----
        o0a += __shfl_xor(o0a, 16); o0a += __shfl_xor(o0a, 32);
        o1a += __shfl_xor(o1a, 16); o1a += __shfl_xor(o1a, 32);
        tra += __shfl_xor(tra, 16); tra += __shfl_xor(tra, 32);
        o0b += __shfl_xor(o0b, 16); o0b += __shfl_xor(o0b, 32);
        o1b += __shfl_xor(o1b, 16); o1b += __shfl_xor(o1b, 32);
        trb += __shfl_xor(trb, 16); trb += __shfl_xor(trb, 32);

        int rowA = tA * 16 + col;
        if (lane < 16 && rowA < B) {
            out[3 * rowA + 0] = o0a + b30;
            out[3 * rowA + 1] = o1a + b31;
            out[3 * rowA + 2] = -tra;
        }
        int rowB = tB * 16 + col;
        if (lane < 16 && vB && rowB < B) {
            out[3 * rowB + 0] = o0b + b30;
            out[3 * rowB + 1] = o1b + b31;
            out[3 * rowB + 2] = -trb;
        }

        zvA = zvAn;
        zvB = zvBn;
    }
}

extern "C" void kernel_launch(void* const* d_in, const int* in_sizes, int n_in,
                              void* d_out, int out_size, void* d_ws, size_t ws_size,
                              hipStream_t stream) {
    // d_in: 0=t(unused) 1=z_and_logp 2=W1 3=b1 4=W2 5=b2 6=W3 7=b3
    const float* zin = (const float*)d_in[1];
    const float* W1  = (const float*)d_in[2];
    const float* b1  = (const float*)d_in[3];
    const float* W2  = (const float*)d_in[4];
    const float* b2  = (const float*)d_in[5];
    const float* W3  = (const float*)d_in[6];
    const float* b3  = (const float*)d_in[7];
    float* out = (float*)d_out;

    int B = in_sizes[1] / 3;
    int ntiles = (B + 15) / 16;
    int grid = 1024;   // 2 waves/SIMD -> 512 resident blocks -> 2 rounds
    odefunc_mfma<<<grid, 256, 0, stream>>>(zin, W1, b1, W2, b2, W3, b3,
                                           out, B, ntiles);
}